// Round 4
// baseline (174.611 us; speedup 1.0000x reference)
//
#include <hip/hip_runtime.h>
#include <hip/hip_bf16.h>
#include <stdint.h>

#define B_    2
#define N_    65536
#define M_    16384
#define K_    32
#define KP_   15
#define DIN_  64
#define DOUT_ 128

typedef __bf16 bf16x8 __attribute__((ext_vector_type(8)));
typedef float  f32x4  __attribute__((ext_vector_type(4)));

__device__ inline float bf2f(unsigned int u) {
    union { unsigned int i; float f; } v; v.i = u << 16; return v.f;
}
__device__ inline unsigned short f2bf(float f) {
    union { float f; unsigned int i; } v; v.f = f;
    unsigned int x = v.i;
    return (unsigned short)((x + 0x7fffu + ((x >> 16) & 1u)) >> 16);  // RNE
}

// ---- K1: features (B, Din, N) f32 -> featT (B, N+1, Din) bf16, row N zeroed ----
__global__ __launch_bounds__(256) void transpose_feats(const float* __restrict__ feats,
                                                       unsigned short* __restrict__ featT) {
    const int b  = blockIdx.y;
    const int n0 = blockIdx.x * 64;
    const int t  = threadIdx.x;
    if (n0 >= N_) {
        if (t < 32)
            ((unsigned int*)(featT + ((size_t)b * (N_ + 1) + N_) * DIN_))[t] = 0u;
        return;
    }
    __shared__ float tile[64][65];
    const int nl = t & 63, dl = t >> 6;
    #pragma unroll
    for (int i = 0; i < 16; ++i) {
        int d = dl + 4 * i;
        tile[d][nl] = feats[((size_t)b * DIN_ + d) * N_ + n0 + nl];
    }
    __syncthreads();
    const int d2 = (t & 31) * 2;
    const int nr = t >> 5;
    #pragma unroll
    for (int i = 0; i < 8; ++i) {
        int n = nr + 8 * i;
        unsigned int u = ((unsigned int)f2bf(tile[d2 + 1][n]) << 16) | f2bf(tile[d2][n]);
        ((unsigned int*)(featT + ((size_t)b * (N_ + 1) + n0 + n) * DIN_))[t & 31] = u;
    }
}

// ---- K2: weights (960,128) f32 -> WT (128,960) bf16 ----
__global__ __launch_bounds__(256) void build_wt(const float* __restrict__ w,
                                                unsigned short* __restrict__ wt) {
    int tid = blockIdx.x * 256 + threadIdx.x;
    if (tid < 960 * 128) {
        int pd = tid >> 7, o = tid & 127;
        wt[o * 960 + pd] = f2bf(w[tid]);
    }
}

// ---- K3: gather + per-lane kernel-weights + MFMA stage-1 -> weighted [B*M][960] bf16 ----
// Stage-1 MFMA: D1[d][p] = sum_k fT[d][k] * w[k][p]
//   A-frag: lane row = d (l&15), 8 k's from LDS (ds_read_u16, XOR-swizzled banks)
//   B-frag: lane col = p (l&15), k-slice (l>>4)*8 -- computed in-register, no LDS
//   D:      col = p, rows = d -> 4 consecutive pd per lane -> one 8B store
__global__ __launch_bounds__(256, 4) void gather_weight_mfma(
    const float* __restrict__ points_xyz,
    const float* __restrict__ center_xyz,
    const int*   __restrict__ nidx,
    const float* __restrict__ kpts,
    const unsigned short* __restrict__ featT,
    unsigned short* __restrict__ weighted) {

    __shared__ __align__(16) char Fb[8 * 32 * 128];   // 32 KB: [m][k] rows of 128B (64 bf16)

    const int t  = threadIdx.x;
    const int b  = blockIdx.y;
    const int m0 = blockIdx.x * 8;
    const size_t ibase = ((size_t)b * M_ + m0) * K_;

    // ---- phase A: gather 8m x 32k feature rows into LDS ----
    const int part = t & 7, rbase = t >> 3;           // pass i = m, rbase = k
    const int kswz = (rbase & 24) << 2;               // 32B-granule XOR by k-slice group
    uint4 v[8];
    #pragma unroll
    for (int i = 0; i < 8; ++i) {
        int n = nidx[ibase + i * 32 + rbase];
        v[i] = *(const uint4*)(featT + ((size_t)b * (N_ + 1) + n) * DIN_ + part * 8);
    }
    #pragma unroll
    for (int i = 0; i < 8; ++i) {
        int byte = (((i * 32 + rbase) << 7) + part * 16) ^ kswz;
        *(uint4*)(Fb + byte) = v[i];
    }
    __syncthreads();

    // ---- phase B: per-lane w + MFMA ----
    const int w0 = t >> 6, l = t & 63;
    const int p  = l & 15, ks = l >> 4;
    const int kp_i = p < KP_ ? p : KP_ - 1;
    const float kpx = kpts[kp_i * 3 + 0];
    const float kpy = kpts[kp_i * 3 + 1];
    const float kpz = kpts[kp_i * 3 + 2];
    const int aswz = ks << 5;                          // matches kswz for k = ks*8+j

    #pragma unroll
    for (int mi = 0; mi < 2; ++mi) {
        const int m  = w0 * 2 + mi;
        const int bm = b * M_ + m0 + m;
        const float cx = center_xyz[bm * 3 + 0];
        const float cy = center_xyz[bm * 3 + 1];
        const float cz = center_xyz[bm * 3 + 2];

        float dx[8], dy[8], dz[8];
        float mymax = 0.f;
        #pragma unroll
        for (int j = 0; j < 8; ++j) {
            int n = nidx[ibase + m * 32 + ks * 8 + j];
            float px, py, pz;
            if (n < N_) {
                const float* pp = points_xyz + ((size_t)b * N_ + n) * 3;
                px = pp[0]; py = pp[1]; pz = pp[2];
            } else { px = py = pz = -1000.0f; }
            dx[j] = px - cx; dy[j] = py - cy; dz[j] = pz - cz;
            float dist = sqrtf(dx[j] * dx[j] + dy[j] * dy[j] + dz[j] * dz[j]);
            mymax = fmaxf(mymax, dist);
        }
        mymax = fmaxf(mymax, __shfl_xor(mymax, 16));
        mymax = fmaxf(mymax, __shfl_xor(mymax, 32));
        const float md   = mymax;
        const float rsig = 1.0f / (md * (1.0f / 2.1f) + 1e-5f);

        union { unsigned short us[8]; bf16x8 v; } wf;   // B-frag: w[k][p] for this lane
        #pragma unroll
        for (int j = 0; j < 8; ++j) {
            float ex = dx[j] - kpx * md;
            float ey = dy[j] - kpy * md;
            float ez = dz[j] - kpz * md;
            float wv = 1.0f - sqrtf(ex * ex + ey * ey + ez * ez) * rsig;
            wf.us[j] = f2bf(wv > 0.f ? wv : 0.f);
        }

        #pragma unroll
        for (int dt = 0; dt < 4; ++dt) {
            union { unsigned short us[8]; bf16x8 v; } af;  // A-frag: fT[d][k]
            #pragma unroll
            for (int j = 0; j < 8; ++j) {
                int byte = (((m * 32 + ks * 8 + j) << 7) + (dt * 16 + p) * 2) ^ aswz;
                af.us[j] = *(const unsigned short*)(Fb + byte);
            }
            f32x4 d1 = __builtin_amdgcn_mfma_f32_16x16x32_bf16(
                af.v, wf.v, (f32x4){0.f, 0.f, 0.f, 0.f}, 0, 0, 0);
            if (p < KP_) {                      // D col = p; rows d = dt*16 + ks*4 + j
                uint2 u;
                u.x = ((unsigned int)f2bf(d1[1]) << 16) | f2bf(d1[0]);
                u.y = ((unsigned int)f2bf(d1[3]) << 16) | f2bf(d1[2]);
                *(uint2*)(weighted + (size_t)bm * 960 + p * 64 + dt * 16 + ks * 4) = u;
            }
        }
    }
}

// ---- K4: out[b][o][m] = weighted[bm][960] x WT[o][960]^T  (MFMA bf16) ----
#define GLOAD_LDS16(g, l) __builtin_amdgcn_global_load_lds( \
    (const __attribute__((address_space(1))) unsigned int*)(g), \
    (__attribute__((address_space(3))) unsigned int*)(l), 16, 0, 0)

__global__ __launch_bounds__(512, 2) void gemm_out(
    const unsigned short* __restrict__ weightedG,   // [32768][960] bf16
    const unsigned short* __restrict__ wtG,         // [128][960]  bf16
    float* __restrict__ out) {

    __shared__ __align__(16) char smem[65536];  // A:[2][16KB] @0, B:[2][16KB] @32768

    const int t = threadIdx.x;
    const int w = t >> 6, lane = t & 63;
    const int bm0 = blockIdx.x * 128;
    const int b = bm0 >> 14, m_in_b = bm0 & (M_ - 1);

    const int wr = w >> 2, wc = w & 3;         // 8 waves: 2 (m) x 4 (o)
    const int wm = wr * 64, wo = wc * 32;      // wave tile: 64 m x 32 o

    f32x4 acc[4][2] = {};

    auto stage = [&](int buf, int kt) {
        #pragma unroll
        for (int i = 0; i < 2; ++i) {          // A-tile: 16 chunks of 1024B, 2/wave
            int chunk = w * 2 + i;
            int L = chunk * 1024 + lane * 16;
            int row = L >> 7, col = L & 127;
            int scol = col ^ ((row & 7) << 4);  // inverse-swizzled SOURCE (linear dest)
            const char* src = (const char*)weightedG + (size_t)(bm0 + row) * 1920 + kt * 128 + scol;
            GLOAD_LDS16(src, smem + buf * 16384 + chunk * 1024);
        }
        #pragma unroll
        for (int i = 0; i < 2; ++i) {          // B-tile (WT rows = o)
            int chunk = w * 2 + i;
            int L = chunk * 1024 + lane * 16;
            int row = L >> 7, col = L & 127;
            int scol = col ^ ((row & 7) << 4);
            const char* src = (const char*)wtG + (size_t)row * 1920 + kt * 128 + scol;
            GLOAD_LDS16(src, smem + 32768 + buf * 16384 + chunk * 1024);
        }
    };

    stage(0, 0);
    __syncthreads();

    for (int kt = 0; kt < 15; ++kt) {
        int cur = kt & 1;
        if (kt < 14) stage(cur ^ 1, kt + 1);
        const char* lA = smem + cur * 16384;
        const char* lB = smem + 32768 + cur * 16384;
        #pragma unroll
        for (int ks = 0; ks < 2; ++ks) {
            bf16x8 af[4], bfr[2];
            const int kcol = ks * 64 + (lane >> 4) * 16;   // byte offset of k-slice
            #pragma unroll
            for (int mf = 0; mf < 4; ++mf) {
                int row = wm + mf * 16 + (lane & 15);
                af[mf] = *(const bf16x8*)(lA + row * 128 + (kcol ^ ((row & 7) << 4)));
            }
            #pragma unroll
            for (int of = 0; of < 2; ++of) {
                int row = wo + of * 16 + (lane & 15);
                bfr[of] = *(const bf16x8*)(lB + row * 128 + (kcol ^ ((row & 7) << 4)));
            }
            #pragma unroll
            for (int mf = 0; mf < 4; ++mf)
                #pragma unroll
                for (int of = 0; of < 2; ++of)
                    acc[mf][of] = __builtin_amdgcn_mfma_f32_16x16x32_bf16(
                        af[mf], bfr[of], acc[mf][of], 0, 0, 0);
        }
        __syncthreads();
    }

    // epilogue: stage D[m][o] -> LDS as [o][m] f32 (swizzled), then coalesced store
    #pragma unroll
    for (int mf = 0; mf < 4; ++mf)
        #pragma unroll
        for (int of = 0; of < 2; ++of) {
            int o  = wo + of * 16 + (lane & 15);        // D col
            int mr = wm + mf * 16 + (lane >> 4) * 4;    // D rows (4 consecutive)
            int byte = (o * 512 + mr * 4) ^ ((o & 7) << 4);
            *(f32x4*)(smem + byte) = acc[mf][of];
        }
    __syncthreads();
    #pragma unroll
    for (int pass = 0; pass < 4; ++pass) {
        int o  = pass * 32 + (t >> 4);
        int mc = (t & 15) * 8;
        int b0 = (o * 512 + mc * 4)       ^ ((o & 7) << 4);
        int b1 = (o * 512 + (mc + 4) * 4) ^ ((o & 7) << 4);
        f32x4 v0 = *(const f32x4*)(smem + b0);
        f32x4 v1 = *(const f32x4*)(smem + b1);
        float* dst = out + ((size_t)(b * DOUT_ + o)) * M_ + m_in_b + mc;
        *(f32x4*)dst = v0;
        *(f32x4*)(dst + 4) = v1;
    }
}

extern "C" void kernel_launch(void* const* d_in, const int* in_sizes, int n_in,
                              void* d_out, int out_size, void* d_ws, size_t ws_size,
                              hipStream_t stream) {
    const float* points_xyz = (const float*)d_in[0];
    const float* features   = (const float*)d_in[1];
    const float* center_xyz = (const float*)d_in[2];
    const int*   nidx       = (const int*)d_in[3];
    const float* kpts       = (const float*)d_in[4];
    const float* weights    = (const float*)d_in[5];
    float* out = (float*)d_out;

    unsigned short* featT    = (unsigned short*)d_ws;                         // 16,777,472 B
    unsigned short* wt       = (unsigned short*)((char*)d_ws + 16777472);     //    245,760 B
    unsigned short* weighted = (unsigned short*)((char*)d_ws + 17023232);     // 62,914,560 B

    transpose_feats<<<dim3((N_ + 64) / 64, B_), 256, 0, stream>>>(features, featT);
    build_wt<<<480, 256, 0, stream>>>(weights, wt);
    gather_weight_mfma<<<dim3(M_ / 8, B_), 256, 0, stream>>>(points_xyz, center_xyz, nidx,
                                                             kpts, featT, weighted);
    gemm_out<<<B_ * M_ / 128, 512, 0, stream>>>(weighted, wt, out);
}

// Round 6
// 153.998 us; speedup vs baseline: 1.1338x; 1.1338x over previous
//
#include <hip/hip_runtime.h>
#include <hip/hip_bf16.h>
#include <stdint.h>

#define B_    2
#define N_    65536
#define M_    16384
#define K_    32
#define KP_   15
#define DIN_  64
#define DOUT_ 128

typedef __bf16 bf16x8 __attribute__((ext_vector_type(8)));
typedef float  f32x4  __attribute__((ext_vector_type(4)));
typedef float  f32x2  __attribute__((ext_vector_type(2)));

__device__ inline unsigned short f2bf(float f) {
    union { float f; unsigned int i; } v; v.f = f;
    unsigned int x = v.i;
    return (unsigned short)((x + 0x7fffu + ((x >> 16) & 1u)) >> 16);  // RNE
}

// ---- K1: features (B, Din, N) f32 -> featT (B, N+1, Din) bf16, row N zeroed ----
__global__ __launch_bounds__(256) void transpose_feats(const float* __restrict__ feats,
                                                       unsigned short* __restrict__ featT) {
    const int b  = blockIdx.y;
    const int n0 = blockIdx.x * 64;
    const int t  = threadIdx.x;
    if (n0 >= N_) {
        if (t < 32)
            ((unsigned int*)(featT + ((size_t)b * (N_ + 1) + N_) * DIN_))[t] = 0u;
        return;
    }
    __shared__ float tile[64][65];
    const int nl = t & 63, dl = t >> 6;
    #pragma unroll
    for (int i = 0; i < 16; ++i) {
        int d = dl + 4 * i;
        tile[d][nl] = feats[((size_t)b * DIN_ + d) * N_ + n0 + nl];
    }
    __syncthreads();
    const int d2 = (t & 31) * 2;
    const int nr = t >> 5;
    #pragma unroll
    for (int i = 0; i < 8; ++i) {
        int n = nr + 8 * i;
        unsigned int u = ((unsigned int)f2bf(tile[d2 + 1][n]) << 16) | f2bf(tile[d2][n]);
        ((unsigned int*)(featT + ((size_t)b * (N_ + 1) + n0 + n) * DIN_))[t & 31] = u;
    }
}

// ---- K2: weights (960,128) f32 -> WT (128,960) bf16 ----
__global__ __launch_bounds__(256) void build_wt(const float* __restrict__ w,
                                                unsigned short* __restrict__ wt) {
    int tid = blockIdx.x * 256 + threadIdx.x;
    if (tid < 960 * 128) {
        int pd = tid >> 7, o = tid & 127;
        wt[o * 960 + pd] = f2bf(w[tid]);
    }
}

// ---- K3: gather + kernel-weights + stage-1 contraction -> weighted [B*M][960] bf16 ----
// w computed once per (m,k) by 256 threads; contraction uses packed-f32 FMA on
// bf16-packed feature pairs (unpack = 2 bit-ops). Fast sqrt/rcp (1e-7 rel, tol 2e-2).
__global__ __launch_bounds__(256, 3) void gather_weight(
    const float* __restrict__ points_xyz,
    const float* __restrict__ center_xyz,
    const int*   __restrict__ nidx,
    const float* __restrict__ kpts,
    const unsigned short* __restrict__ featT,
    unsigned short* __restrict__ weighted) {

    __shared__ __align__(16) float        wlds[8 * KP_ * 32];   // [m][p][k] 15.4 KB, stride 32
    __shared__ __align__(16) unsigned int fbuf[8 * 32 * 32];    // [m][k][d2] 32 KB

    const int t  = threadIdx.x;
    const int b  = blockIdx.y;
    const int m0 = blockIdx.x * 8;
    const size_t ibase = ((size_t)b * M_ + m0) * K_;

    // (1) issue all feature gathers into regs (latency hides under w-compute)
    uint4 v[8];
    const int part = t & 7, rbase = t >> 3;
    #pragma unroll
    for (int i = 0; i < 8; ++i) {
        int r = i * 32 + rbase;                   // r = m*32 + k
        int n = nidx[ibase + r];
        v[i] = *(const uint4*)(featT + ((size_t)b * (N_ + 1) + n) * DIN_ + part * 8);
    }

    // (2) kernel-correlation weights: thread = (m = t>>5, k = t&31), all 256 active
    {
        const int m = t >> 5, k = t & 31;
        int n = nidx[ibase + t];
        float px, py, pz;
        if (n < N_) {
            const float* p = points_xyz + ((size_t)b * N_ + n) * 3;
            px = p[0]; py = p[1]; pz = p[2];
        } else {
            px = py = pz = -1000.0f;
        }
        const float* c = center_xyz + ((size_t)b * M_ + m0 + m) * 3;
        float dx = px - c[0], dy = py - c[1], dz = pz - c[2];
        float md = __builtin_amdgcn_sqrtf(dx * dx + dy * dy + dz * dz);
        #pragma unroll
        for (int s = 16; s > 0; s >>= 1)
            md = fmaxf(md, __shfl_xor(md, s));
        float rsig = __builtin_amdgcn_rcpf(md * (1.0f / 2.1f) + 1e-5f);
        #pragma unroll
        for (int p = 0; p < KP_; ++p) {
            float ex = dx - kpts[p * 3 + 0] * md;
            float ey = dy - kpts[p * 3 + 1] * md;
            float ez = dz - kpts[p * 3 + 2] * md;
            float wv = 1.0f - __builtin_amdgcn_sqrtf(ex * ex + ey * ey + ez * ez) * rsig;
            wlds[(m * KP_ + p) * 32 + k] = wv > 0.0f ? wv : 0.0f;  // k-indexed: conflict-free
        }
    }

    // (3) land gathers in LDS (vmcnt waits here, after w-compute)
    #pragma unroll
    for (int i = 0; i < 8; ++i)
        ((uint4*)fbuf)[(i * 32 + rbase) * 8 + part] = v[i];
    __syncthreads();

    // (4) weighted[m][p][2*d2..+1] = sum_k w[m][p][k] * f[m][k][d-pair]; packed-f32 FMA
    const int m = t >> 5, d2 = t & 31;
    f32x2 acc[KP_];
    #pragma unroll
    for (int p = 0; p < KP_; ++p) acc[p] = (f32x2){0.f, 0.f};

    const unsigned int* fcol = &fbuf[(m * 32) * 32 + d2];
    const float* wbase = &wlds[m * KP_ * 32];

    #pragma unroll
    for (int k4 = 0; k4 < 8; ++k4) {
        f32x2 fv[4];
        #pragma unroll
        for (int j = 0; j < 4; ++j) {
            unsigned int u = fcol[(k4 * 4 + j) * 32];
            union { unsigned int i; float f; } lo, hi;
            lo.i = u << 16; hi.i = u & 0xffff0000u;
            fv[j] = (f32x2){lo.f, hi.f};
        }
        #pragma unroll
        for (int p = 0; p < KP_; ++p) {
            float4 w4 = *(const float4*)(wbase + p * 32 + k4 * 4);  // broadcast read
            acc[p] += fv[0] * w4.x;
            acc[p] += fv[1] * w4.y;
            acc[p] += fv[2] * w4.z;
            acc[p] += fv[3] * w4.w;
        }
    }

    unsigned int* wout = (unsigned int*)weighted + (size_t)(b * M_ + m0 + m) * 480 + d2;
    #pragma unroll
    for (int p = 0; p < KP_; ++p) {
        unsigned int u = ((unsigned int)f2bf(acc[p][1]) << 16) | f2bf(acc[p][0]);
        wout[p * 32] = u;
    }
}

// ---- K4: out[b][o][m] = weighted[bm][960] x WT[o][960]^T  (MFMA bf16) ----
#define GLOAD_LDS16(g, l) __builtin_amdgcn_global_load_lds( \
    (const __attribute__((address_space(1))) unsigned int*)(g), \
    (__attribute__((address_space(3))) unsigned int*)(l), 16, 0, 0)

__global__ __launch_bounds__(512, 2) void gemm_out(
    const unsigned short* __restrict__ weightedG,   // [32768][960] bf16
    const unsigned short* __restrict__ wtG,         // [128][960]  bf16
    float* __restrict__ out) {

    __shared__ __align__(16) char smem[65536];  // A:[2][16KB] @0, B:[2][16KB] @32768

    const int t = threadIdx.x;
    const int w = t >> 6, lane = t & 63;
    const int bm0 = blockIdx.x * 128;
    const int b = bm0 >> 14, m_in_b = bm0 & (M_ - 1);

    const int wr = w >> 2, wc = w & 3;         // 8 waves: 2 (m) x 4 (o)
    const int wm = wr * 64, wo = wc * 32;      // wave tile: 64 m x 32 o

    f32x4 acc[4][2] = {};

    auto stage = [&](int buf, int kt) {
        #pragma unroll
        for (int i = 0; i < 2; ++i) {          // A-tile: 16 chunks of 1024B, 2/wave
            int chunk = w * 2 + i;
            int L = chunk * 1024 + lane * 16;
            int row = L >> 7, col = L & 127;
            int scol = col ^ ((row & 7) << 4);  // inverse-swizzled SOURCE (linear dest)
            const char* src = (const char*)weightedG + (size_t)(bm0 + row) * 1920 + kt * 128 + scol;
            GLOAD_LDS16(src, smem + buf * 16384 + chunk * 1024);
        }
        #pragma unroll
        for (int i = 0; i < 2; ++i) {          // B-tile (WT rows = o)
            int chunk = w * 2 + i;
            int L = chunk * 1024 + lane * 16;
            int row = L >> 7, col = L & 127;
            int scol = col ^ ((row & 7) << 4);
            const char* src = (const char*)wtG + (size_t)row * 1920 + kt * 128 + scol;
            GLOAD_LDS16(src, smem + 32768 + buf * 16384 + chunk * 1024);
        }
    };

    stage(0, 0);
    __syncthreads();

    for (int kt = 0; kt < 15; ++kt) {
        int cur = kt & 1;
        if (kt < 14) stage(cur ^ 1, kt + 1);
        const char* lA = smem + cur * 16384;
        const char* lB = smem + 32768 + cur * 16384;
        #pragma unroll
        for (int ks = 0; ks < 2; ++ks) {
            bf16x8 af[4], bfr[2];
            const int kcol = ks * 64 + (lane >> 4) * 16;   // byte offset of k-slice
            #pragma unroll
            for (int mf = 0; mf < 4; ++mf) {
                int row = wm + mf * 16 + (lane & 15);
                af[mf] = *(const bf16x8*)(lA + row * 128 + (kcol ^ ((row & 7) << 4)));
            }
            #pragma unroll
            for (int of = 0; of < 2; ++of) {
                int row = wo + of * 16 + (lane & 15);
                bfr[of] = *(const bf16x8*)(lB + row * 128 + (kcol ^ ((row & 7) << 4)));
            }
            #pragma unroll
            for (int mf = 0; mf < 4; ++mf)
                #pragma unroll
                for (int of = 0; of < 2; ++of)
                    acc[mf][of] = __builtin_amdgcn_mfma_f32_16x16x32_bf16(
                        af[mf], bfr[of], acc[mf][of], 0, 0, 0);
        }
        __syncthreads();
    }

    // epilogue: stage D[m][o] -> LDS as [o][m] f32 (swizzled), then coalesced store
    #pragma unroll
    for (int mf = 0; mf < 4; ++mf)
        #pragma unroll
        for (int of = 0; of < 2; ++of) {
            int o  = wo + of * 16 + (lane & 15);        // D col
            int mr = wm + mf * 16 + (lane >> 4) * 4;    // D rows (4 consecutive)
            int byte = (o * 512 + mr * 4) ^ ((o & 7) << 4);
            *(f32x4*)(smem + byte) = acc[mf][of];
        }
    __syncthreads();
    #pragma unroll
    for (int pass = 0; pass < 4; ++pass) {
        int o  = pass * 32 + (t >> 4);
        int mc = (t & 15) * 8;
        int b0 = (o * 512 + mc * 4)       ^ ((o & 7) << 4);
        int b1 = (o * 512 + (mc + 4) * 4) ^ ((o & 7) << 4);
        f32x4 v0 = *(const f32x4*)(smem + b0);
        f32x4 v1 = *(const f32x4*)(smem + b1);
        float* dst = out + ((size_t)(b * DOUT_ + o)) * M_ + m_in_b + mc;
        *(f32x4*)dst = v0;
        *(f32x4*)(dst + 4) = v1;
    }
}

extern "C" void kernel_launch(void* const* d_in, const int* in_sizes, int n_in,
                              void* d_out, int out_size, void* d_ws, size_t ws_size,
                              hipStream_t stream) {
    const float* points_xyz = (const float*)d_in[0];
    const float* features   = (const float*)d_in[1];
    const float* center_xyz = (const float*)d_in[2];
    const int*   nidx       = (const int*)d_in[3];
    const float* kpts       = (const float*)d_in[4];
    const float* weights    = (const float*)d_in[5];
    float* out = (float*)d_out;

    unsigned short* featT    = (unsigned short*)d_ws;                         // 16,777,472 B
    unsigned short* wt       = (unsigned short*)((char*)d_ws + 16777472);     //    245,760 B
    unsigned short* weighted = (unsigned short*)((char*)d_ws + 17023232);     // 62,914,560 B

    transpose_feats<<<dim3((N_ + 64) / 64, B_), 256, 0, stream>>>(features, featT);
    build_wt<<<480, 256, 0, stream>>>(weights, wt);
    gather_weight<<<dim3(M_ / 8, B_), 256, 0, stream>>>(points_xyz, center_xyz, nidx,
                                                        kpts, featT, weighted);
    gemm_out<<<B_ * M_ / 128, 512, 0, stream>>>(weighted, wt, out);
}